// Round 12
// baseline (450.506 us; speedup 1.0000x reference)
//
#include <hip/hip_runtime.h>
#include <hip/hip_bf16.h>

typedef float f32x4 __attribute__((ext_vector_type(4)));
typedef short s16x8 __attribute__((ext_vector_type(8)));
typedef short s16x4 __attribute__((ext_vector_type(4)));
typedef unsigned short u16;

#define HIDDEN 4096
#define NQ 32
#define NKV 8
#define HD 128
#define T_SEQ 2048
#define QKV_N ((NQ + 2 * NKV) * HD)   // 6144

__device__ __forceinline__ u16 f2bf(float f) {
    union { float f; unsigned u; } v; v.f = f;
    unsigned r = v.u + 0x7FFFu + ((v.u >> 16) & 1u);
    return (u16)(r >> 16);
}
__device__ __forceinline__ float b2f(u16 h) {
    union { unsigned u; float f; } v; v.u = ((unsigned)h) << 16; return v.f;
}
__device__ __forceinline__ void gload_lds16(const u16* g, u16* l) {
    __builtin_amdgcn_global_load_lds(
        (const __attribute__((address_space(1))) unsigned int*)g,
        (__attribute__((address_space(3))) unsigned int*)l,
        16, 0, 0);
}
// bijective XCD remap (nwg % 8 == 0): contiguous chunk per XCD
__device__ __forceinline__ int xcd_swz(int flat, int nwg) {
    return (flat & 7) * (nwg >> 3) + (flat >> 3);
}

// ---------------- f32 -> bf16 bulk convert ----------------
__device__ __forceinline__ void conv8(const float* src, u16* dst, int i) {
    const float4 a = ((const float4*)src)[2 * i];
    const float4 b = ((const float4*)src)[2 * i + 1];
    s16x8 o;
    o[0] = (short)f2bf(a.x); o[1] = (short)f2bf(a.y);
    o[2] = (short)f2bf(a.z); o[3] = (short)f2bf(a.w);
    o[4] = (short)f2bf(b.x); o[5] = (short)f2bf(b.y);
    o[6] = (short)f2bf(b.z); o[7] = (short)f2bf(b.w);
    ((s16x8*)dst)[i] = o;
}
__global__ __launch_bounds__(256) void conv_bf16_kern(
    const float* __restrict__ src, u16* __restrict__ dst, int n8)
{
    for (int i = blockIdx.x * 256 + threadIdx.x; i < n8; i += gridDim.x * 256)
        conv8(src, dst, i);
}

// ---------------- GEMM: C[M,N] = A[M,K] * B[N,K]^T ----------------
// A: bf16 via global_load_lds. B: bf16 (BF32=0) or f32 (BF32=1) with fused
// conversion, DEEP-pipelined (load tile k+2 while computing k; write tile k+1
// loaded a full iteration earlier — r11's same-iter load->write exposed HBM
// latency every iter, 124->200us). Static p0/p1 reg buffers, loop unrolled x2.
// vmcnt: queue at sub-iter = B(k+1)[4],A(k)[2],B(k+2)[4],A(k+1)[2] -> vmcnt(6)
// drains exactly {B(k+1), A(k)}; tails 2/0. nk must be even for BF32 (128 here).
template<int OUT_BF16, int BF32>
__global__ __launch_bounds__(256) void gemm_bt(
    const u16* __restrict__ A, const void* __restrict__ Bv,
    void* __restrict__ Cv, int N, int K)
{
    __shared__ u16 As[2][128 * 32];
    __shared__ u16 Bs[2][128 * 32];
    const int tid = threadIdx.x, lane = tid & 63, wid = tid >> 6;
    const int wr = wid >> 1, wc = wid & 1, lg = lane >> 4, l15 = lane & 15;
    const int m0 = blockIdx.y * 128, n0 = blockIdx.x * 128;
    const int srow = wid * 32 + (lane >> 2);
    const int scol = (((lane & 3) ^ ((lane >> 3) & 3))) * 8;
    const u16* ga = &A[(size_t)(m0 + srow) * K + scol];
    const u16* gb = &((const u16*)Bv)[(size_t)(n0 + srow) * K + scol];
    // f32-B geometry: thread owns row rB = tid>>1, chunks {c2, c2+1}
    const int rB = tid >> 1, c2 = (tid & 1) * 2;
    const int psB = (rB >> 1) & 3;                     // write-side swizzle
    const float* gbf = &((const float*)Bv)[(size_t)(n0 + rB) * K + c2 * 8];
    const int rsw = (lg ^ ((l15 >> 1) & 3)) * 8;       // read-side swizzle

    f32x4 acc[4][4] = {};
    const int nk = K >> 5;
    float4 p0a, p0b, p0c, p0d, p1a, p1b, p1c, p1d;     // 2 reg buffers (static)

    auto stageA = [&](int buf, int koff) {
        u16* la = &As[buf][wid * 1024];
        gload_lds16(ga + koff, la);
        gload_lds16(ga + koff + 16 * K, la + 512);
    };
    auto stageBlds = [&](int buf, int koff) {
        u16* lb = &Bs[buf][wid * 1024];
        gload_lds16(gb + koff, lb);
        gload_lds16(gb + koff + 16 * K, lb + 512);
    };
#define LOADB(pa, pb, pc, pd, koff) do { \
    pa = *(const float4*)(gbf + (koff)); \
    pb = *(const float4*)(gbf + (koff) + 4); \
    pc = *(const float4*)(gbf + (koff) + 8); \
    pd = *(const float4*)(gbf + (koff) + 12); } while (0)
#define WRITEB(pa, pb, pc, pd, buf) do { \
    s16x8 lo, hi; \
    lo[0] = (short)f2bf(pa.x); lo[1] = (short)f2bf(pa.y); \
    lo[2] = (short)f2bf(pa.z); lo[3] = (short)f2bf(pa.w); \
    lo[4] = (short)f2bf(pb.x); lo[5] = (short)f2bf(pb.y); \
    lo[6] = (short)f2bf(pb.z); lo[7] = (short)f2bf(pb.w); \
    hi[0] = (short)f2bf(pc.x); hi[1] = (short)f2bf(pc.y); \
    hi[2] = (short)f2bf(pc.z); hi[3] = (short)f2bf(pc.w); \
    hi[4] = (short)f2bf(pd.x); hi[5] = (short)f2bf(pd.y); \
    hi[6] = (short)f2bf(pd.z); hi[7] = (short)f2bf(pd.w); \
    *(s16x8*)&Bs[buf][rB * 32 + ((c2    ) ^ psB) * 8] = lo; \
    *(s16x8*)&Bs[buf][rB * 32 + ((c2 + 1) ^ psB) * 8] = hi; } while (0)

    auto mfma_step = [&](int buf) {
        s16x8 af[4], bfr[4];
#pragma unroll
        for (int i = 0; i < 4; ++i) af[i]  = *(const s16x8*)&As[buf][(wr * 64 + i * 16 + l15) * 32 + rsw];
#pragma unroll
        for (int j = 0; j < 4; ++j) bfr[j] = *(const s16x8*)&Bs[buf][(wc * 64 + j * 16 + l15) * 32 + rsw];
#pragma unroll
        for (int i = 0; i < 4; ++i)
#pragma unroll
            for (int j = 0; j < 4; ++j)
                acc[i][j] = __builtin_amdgcn_mfma_f32_16x16x32_bf16(af[i], bfr[j], acc[i][j], 0, 0, 0);
    };

    if (BF32) {
        // prologue: tile0 -> p0 -> Bs[0]; tile1 -> p1 (written in first sub-A)
        LOADB(p0a, p0b, p0c, p0d, 0);
        stageA(0, 0);
        WRITEB(p0a, p0b, p0c, p0d, 0);                 // compiler waits p0 loads
        LOADB(p1a, p1b, p1c, p1d, 32);
        for (int kk = 0; kk < nk; kk += 2) {
            // ---- sub-iter A: compute tile kk (buf0); prefetch kk+2 -> p0
            if (kk + 2 < nk) LOADB(p0a, p0b, p0c, p0d, (kk + 2) * 32);
            stageA(1, (kk + 1) * 32);
            if (kk + 2 < nk)
                asm volatile("s_waitcnt vmcnt(6)" ::: "memory");
            else
                asm volatile("s_waitcnt vmcnt(2)" ::: "memory");
            __builtin_amdgcn_s_barrier();
            mfma_step(0);
            WRITEB(p1a, p1b, p1c, p1d, 1);             // tile kk+1 (loaded @ kk-1)
            __builtin_amdgcn_s_barrier();
            // ---- sub-iter B: compute tile kk+1 (buf1); prefetch kk+3 -> p1
            if (kk + 3 < nk) LOADB(p1a, p1b, p1c, p1d, (kk + 3) * 32);
            if (kk + 2 < nk) stageA(0, (kk + 2) * 32);
            if (kk + 3 < nk)
                asm volatile("s_waitcnt vmcnt(6)" ::: "memory");
            else
                asm volatile("s_waitcnt vmcnt(0)" ::: "memory");
            __builtin_amdgcn_s_barrier();
            mfma_step(1);
            if (kk + 2 < nk) WRITEB(p0a, p0b, p0c, p0d, 0);  // tile kk+2
            __builtin_amdgcn_s_barrier();
        }
    } else {
        stageA(0, 0);
        stageBlds(0, 0);
        for (int kk = 0; kk < nk; ++kk) {
            const int cur = kk & 1;
            if (kk + 1 < nk) {
                stageA(cur ^ 1, (kk + 1) * 32);
                stageBlds(cur ^ 1, (kk + 1) * 32);
                asm volatile("s_waitcnt vmcnt(4)" ::: "memory");
            } else {
                asm volatile("s_waitcnt vmcnt(0)" ::: "memory");
            }
            __builtin_amdgcn_s_barrier();
            mfma_step(cur);
            __builtin_amdgcn_s_barrier();
        }
    }
#pragma unroll
    for (int i = 0; i < 4; ++i) {
        int r0 = m0 + wr * 64 + i * 16 + lg * 4;
#pragma unroll
        for (int j = 0; j < 4; ++j) {
            int cc = n0 + wc * 64 + j * 16 + l15;
#pragma unroll
            for (int r = 0; r < 4; ++r) {
                if (OUT_BF16)
                    ((u16*)Cv)[(size_t)(r0 + r) * N + cc] = f2bf(acc[i][j][r]);
                else
                    ((float*)Cv)[(size_t)(r0 + r) * N + cc] = acc[i][j][r];
            }
        }
    }
#undef LOADB
#undef WRITEB
}

// ---------------- Fused RMSNorm+RoPE and V-transpose ----------------
__global__ __launch_bounds__(256) void nr_vt_kern(
    const u16* __restrict__ qkv, const float* __restrict__ qw,
    const float* __restrict__ kw, u16* __restrict__ qr, u16* __restrict__ kr,
    u16* __restrict__ vt)
{
    __shared__ u16 Ts[128][66];
    const int id = blockIdx.x, tid = threadIdx.x;
    if (id < 20480) {
        const int t = id & 2047, h = (id >> 11) * 4 + (tid >> 6);
        const int i = tid & 63;
        const size_t rowbase = (size_t)t * QKV_N;
        const u16* src; const float* w; u16* dst;
        if (h < 32) {
            src = qkv + rowbase + h * HD; w = qw;
            dst = qr + ((size_t)h * T_SEQ + t) * HD;
        } else {
            int kh = h - 32;
            src = qkv + rowbase + NQ * HD + kh * HD; w = kw;
            dst = kr + ((size_t)kh * T_SEQ + t) * HD;
        }
        float x1 = b2f(src[i]), x2 = b2f(src[i + 64]);
        float ss = x1 * x1 + x2 * x2;
#pragma unroll
        for (int d = 32; d >= 1; d >>= 1) ss += __shfl_xor(ss, d);
        float rs = rsqrtf(ss * (1.0f / 128.0f) + 1e-6f);
        x1 *= rs * w[i];
        x2 *= rs * w[i + 64];
        float ang = (float)t * exp2f((float)i * -0.20762050593567985f);
        float sn, cs;
        sincosf(ang, &sn, &cs);
        dst[i]      = f2bf(x1 * cs - x2 * sn);
        dst[i + 64] = f2bf(x2 * cs + x1 * sn);
        return;
    }
    const int id2 = id - 20480;
    const int t0 = (id2 & 31) * 64, kh = id2 >> 5;
#pragma unroll
    for (int it = 0; it < 4; ++it) {
        int slot = tid + it * 256;
        int tl = slot >> 4, dc = (slot & 15) * 8;
        s16x8 v = *(const s16x8*)&qkv[(size_t)(t0 + tl) * QKV_N + (NQ + NKV) * HD + kh * HD + dc];
#pragma unroll
        for (int e = 0; e < 8; ++e) Ts[dc + e][tl] = (u16)v[e];
    }
    __syncthreads();
#pragma unroll
    for (int it = 0; it < 4; ++it) {
        int slot = tid + it * 256;
        int d = slot >> 3, c = (slot & 7) * 8;
        s16x8 v = *(const s16x8*)&Ts[d][c];
        *(s16x8*)&vt[((size_t)kh * HD + d) * T_SEQ + t0 + c] = v;
    }
}

// ---------------- Flash attention (causal, GQA), swapped-QK^T, QBLK=128 --------
// grid (8, NQ) = 256 blocks, 512 thr = 8 waves. Dbuf K/V, 1 barrier/tile.
// Each block also converts its 256KB slice of wo (f32->bf16), software-pipelined
// 1 chunk/thread/K-tile — rides the idle VMEM pipe under MFMA.
#define KS(b, r, c) Ks[(b)][((r) << 7) + ((c) ^ (((r) & 7) << 3))]
#define VS(b, r, c) Vs[(b)][((r) << 6) + ((c) ^ (((r) & 7) << 3))]
#define PS(wv, r, c) Ps[((wv) << 10) + ((r) << 6) + ((c) ^ (((r) & 7) << 3))]

__global__ __launch_bounds__(512) void attn_kern(
    const u16* __restrict__ qr, const u16* __restrict__ kr,
    const u16* __restrict__ vt, u16* __restrict__ o,
    const float* __restrict__ wo, u16* __restrict__ wo_bf)
{
    __shared__ u16 Ks[2][64 * 128];
    __shared__ u16 Vs[2][128 * 64];
    __shared__ u16 Ps[8 * 16 * 64];
    const int tid = threadIdx.x, lane = tid & 63, w = tid >> 6;   // w: 0..7
    const int lg = lane >> 4, l15 = lane & 15;
    const int fb = (int)blockIdx.y * 8 + (int)blockIdx.x;         // 0..255
    const int flat = xcd_swz(fb, 256);
    const int qh = flat >> 3, bx = flat & 7;
    const int kvh = qh >> 2;
    const float scale2 = 0.08838834764831845f * 1.4426950408889634f;  // 1/sqrt(128)*log2e

    const int cvbase = fb * 8192 + tid;   // wo chunks owned by this block
    int cv = 0;
    float4 cva = {}, cvb = {};

    const int krow = tid >> 4, kcol = (tid & 15) * 8;
    const int vrow = tid >> 3, vcol = (tid & 7) * 8;
    const u16* krbase = kr + (size_t)kvh * T_SEQ * HD;
    const u16* vtbase = vt + (size_t)kvh * HD * T_SEQ;

    s16x8 kst[2], vst[2];
#define LOADKV(k0_) do { \
    kst[0] = *(const s16x8*)&krbase[(size_t)((k0_) + krow) * HD + kcol]; \
    kst[1] = *(const s16x8*)&krbase[(size_t)((k0_) + krow + 32) * HD + kcol]; \
    vst[0] = *(const s16x8*)&vtbase[(size_t)(vrow) * T_SEQ + (k0_) + vcol]; \
    vst[1] = *(const s16x8*)&vtbase[(size_t)(vrow + 64) * T_SEQ + (k0_) + vcol]; \
    } while (0)
#define WRITEKV(b) do { \
    *(s16x8*)&KS((b), krow, kcol) = kst[0]; \
    *(s16x8*)&KS((b), krow + 32, kcol) = kst[1]; \
    *(s16x8*)&VS((b), vrow, vcol) = vst[0]; \
    *(s16x8*)&VS((b), vrow + 64, vcol) = vst[1]; \
    } while (0)

    for (int half = 0; half < 2; ++half) {
        const int q0 = (half == 0) ? bx * 128 : (T_SEQ - 128) - bx * 128;
        s16x8 qf[4];
        {
            const u16* qb = qr + ((size_t)qh * T_SEQ + q0 + w * 16 + l15) * HD;
#pragma unroll
            for (int dc = 0; dc < 4; ++dc) qf[dc] = *(const s16x8*)&qb[dc * 32 + lg * 8];
        }
        f32x4 oacc[8] = {};
        float mQ = -1e30f, lsQ = 0.f;

        const int ktiles = (q0 >> 6) + 2;
        LOADKV(0);
        WRITEKV(0);
        __syncthreads();
        for (int kt = 0; kt < ktiles; ++kt) {
            const int k0 = kt * 64;
            const int cur = kt & 1;
            if (kt + 1 < ktiles) LOADKV(k0 + 64);

            if (cv <= 16) {
                if (cv > 0) {
                    s16x8 o8;
                    o8[0] = (short)f2bf(cva.x); o8[1] = (short)f2bf(cva.y);
                    o8[2] = (short)f2bf(cva.z); o8[3] = (short)f2bf(cva.w);
                    o8[4] = (short)f2bf(cvb.x); o8[5] = (short)f2bf(cvb.y);
                    o8[6] = (short)f2bf(cvb.z); o8[7] = (short)f2bf(cvb.w);
                    ((s16x8*)wo_bf)[cvbase + (cv - 1) * 512] = o8;
                }
                if (cv < 16) {
                    cva = ((const float4*)wo)[2 * (cvbase + cv * 512)];
                    cvb = ((const float4*)wo)[2 * (cvbase + cv * 512) + 1];
                }
                ++cv;
            }

            f32x4 sc[4] = {};
            __builtin_amdgcn_s_setprio(1);
#pragma unroll
            for (int nc = 0; nc < 4; ++nc)
#pragma unroll
                for (int dc = 0; dc < 4; ++dc) {
                    s16x8 kf = *(const s16x8*)&KS(cur, nc * 16 + l15, dc * 32 + lg * 8);
                    sc[nc] = __builtin_amdgcn_mfma_f32_16x16x32_bf16(kf, qf[dc], sc[nc], 0, 0, 0);
                }
            __builtin_amdgcn_s_setprio(0);

            const int qg = q0 + w * 16 + l15;
            const bool needMask = (k0 + 63) > (q0 + w * 16);
            float tm = -1e30f;
#pragma unroll
            for (int nc = 0; nc < 4; ++nc)
#pragma unroll
                for (int r = 0; r < 4; ++r) {
                    float v = sc[nc][r] * scale2;
                    int kg = k0 + nc * 16 + lg * 4 + r;
                    if (needMask && kg > qg) v = -1e30f;
                    sc[nc][r] = v;
                    tm = fmaxf(tm, v);
                }
            tm = fmaxf(tm, __shfl_xor(tm, 16));
            tm = fmaxf(tm, __shfl_xor(tm, 32));

            if (__any(tm > mQ + 8.0f)) {
                float mn = fmaxf(mQ, tm);
                float alpha = exp2f(mQ - mn);
                mQ = mn;
                lsQ *= alpha;
                float aq[4];
#pragma unroll
                for (int r = 0; r < 4; ++r) aq[r] = __shfl(alpha, lg * 4 + r);
#pragma unroll
                for (int dc = 0; dc < 8; ++dc)
#pragma unroll
                    for (int r = 0; r < 4; ++r) oacc[dc][r] *= aq[r];
            }

            float ts = 0.f;
#pragma unroll
            for (int nc = 0; nc < 4; ++nc) {
                s16x4 pk;
#pragma unroll
                for (int r = 0; r < 4; ++r) {
                    float e = exp2f(sc[nc][r] - mQ);
                    ts += e;
                    pk[r] = (short)f2bf(e);
                }
                *(s16x4*)&PS(w, l15, nc * 16 + lg * 4) = pk;
            }
            ts += __shfl_xor(ts, 16);
            ts += __shfl_xor(ts, 32);
            lsQ += ts;

            __builtin_amdgcn_s_setprio(1);
#pragma unroll
            for (int kc = 0; kc < 2; ++kc) {
                s16x8 pf = *(const s16x8*)&PS(w, l15, kc * 32 + lg * 8);
#pragma unroll
                for (int dc = 0; dc < 8; ++dc) {
                    s16x8 vf = *(const s16x8*)&VS(cur, dc * 16 + l15, kc * 32 + lg * 8);
                    oacc[dc] = __builtin_amdgcn_mfma_f32_16x16x32_bf16(pf, vf, oacc[dc], 0, 0, 0);
                }
            }
            __builtin_amdgcn_s_setprio(0);

            if (kt + 1 < ktiles) WRITEKV(cur ^ 1);
            __syncthreads();
        }
        float lq[4];
#pragma unroll
        for (int r = 0; r < 4; ++r) lq[r] = __shfl(lsQ, lg * 4 + r);
#pragma unroll
        for (int r = 0; r < 4; ++r) {
            float inv = 1.0f / lq[r];
            int trow = q0 + w * 16 + lg * 4 + r;
            u16* dst = o + (size_t)trow * (NQ * HD) + qh * HD;
#pragma unroll
            for (int dc = 0; dc < 8; ++dc) dst[dc * 16 + l15] = f2bf(oacc[dc][r] * inv);
        }
    }
#undef LOADKV
#undef WRITEKV
}

extern "C" void kernel_launch(void* const* d_in, const int* in_sizes, int n_in,
                              void* d_out, int out_size, void* d_ws, size_t ws_size,
                              hipStream_t stream)
{
    const float* hs   = (const float*)d_in[0];
    const float* wqkv = (const float*)d_in[1];
    const float* qw   = (const float*)d_in[2];
    const float* kw   = (const float*)d_in[3];
    const float* wo   = (const float*)d_in[4];
    float* out = (float*)d_out;

    // workspace layout, 92,274,688 B total; regions reused across disjoint lifetimes:
    //   [ 0,16M)  hs_bf      -> ob (after gemm1)
    //   [16,40M)  qr[16,32M), kr[32,36M), vt[36,40M)
    //   [40,72M)  wo_bf (written during attn; overlaps dead qkv_bf tail)
    //   [64,88M)  qkv_bf (dead after nr_vt)
    char* ws = (char*)d_ws;
    u16* hs_bf   = (u16*)(ws);
    u16* ob      = (u16*)(ws);
    u16* qr      = (u16*)(ws + 16777216);
    u16* kr      = (u16*)(ws + 33554432);
    u16* vt      = (u16*)(ws + 37748736);
    u16* wo_bf   = (u16*)(ws + 41943040);
    u16* qkv_bf  = (u16*)(ws + 67108864);

    // 1) convert hs only (wqkv consumed as f32 by gemm1's deep-pipelined staging)
    conv_bf16_kern<<<2048, 256, 0, stream>>>(hs, hs_bf, T_SEQ * HIDDEN / 8);
    // 2) qkv = hs @ wqkv^T, B = raw f32 weights
    gemm_bt<1, 1><<<dim3(QKV_N / 128, T_SEQ / 128), 256, 0, stream>>>(
        hs_bf, (const void*)wqkv, (void*)qkv_bf, QKV_N, HIDDEN);
    // 3) fused norm+rope / V-transpose (last readers of qkv_bf)
    nr_vt_kern<<<20736, 256, 0, stream>>>(qkv_bf, qw, kw, qr, kr, vt);
    // 4) attention with embedded wo conversion
    attn_kern<<<dim3(8, NQ), 512, 0, stream>>>(qr, kr, vt, ob, wo, wo_bf);
    // 5) out = o @ wo^T (B = bf16 produced by attn)
    gemm_bt<0, 0><<<dim3(HIDDEN / 128, T_SEQ / 128), 256, 0, stream>>>(
        ob, (const void*)wo_bf, (void*)out, HIDDEN, HIDDEN);
}

// Round 13
// 370.877 us; speedup vs baseline: 1.2147x; 1.2147x over previous
//
#include <hip/hip_runtime.h>
#include <hip/hip_bf16.h>

typedef float f32x4 __attribute__((ext_vector_type(4)));
typedef short s16x8 __attribute__((ext_vector_type(8)));
typedef short s16x4 __attribute__((ext_vector_type(4)));
typedef unsigned short u16;

#define HIDDEN 4096
#define NQ 32
#define NKV 8
#define HD 128
#define T_SEQ 2048
#define QKV_N ((NQ + 2 * NKV) * HD)   // 6144

__device__ __forceinline__ u16 f2bf(float f) {
    union { float f; unsigned u; } v; v.f = f;
    unsigned r = v.u + 0x7FFFu + ((v.u >> 16) & 1u);
    return (u16)(r >> 16);
}
__device__ __forceinline__ float b2f(u16 h) {
    union { unsigned u; float f; } v; v.u = ((unsigned)h) << 16; return v.f;
}
__device__ __forceinline__ void gload_lds16(const u16* g, u16* l) {
    __builtin_amdgcn_global_load_lds(
        (const __attribute__((address_space(1))) unsigned int*)g,
        (__attribute__((address_space(3))) unsigned int*)l,
        16, 0, 0);
}
// bijective XCD remap (nwg % 8 == 0): contiguous chunk per XCD
__device__ __forceinline__ int xcd_swz(int flat, int nwg) {
    return (flat & 7) * (nwg >> 3) + (flat >> 3);
}

// ---------------- f32 -> bf16 bulk convert (two segments) ----------------
__device__ __forceinline__ void conv8(const float* src, u16* dst, int i) {
    const float4 a = ((const float4*)src)[2 * i];
    const float4 b = ((const float4*)src)[2 * i + 1];
    s16x8 o;
    o[0] = (short)f2bf(a.x); o[1] = (short)f2bf(a.y);
    o[2] = (short)f2bf(a.z); o[3] = (short)f2bf(a.w);
    o[4] = (short)f2bf(b.x); o[5] = (short)f2bf(b.y);
    o[6] = (short)f2bf(b.z); o[7] = (short)f2bf(b.w);
    ((s16x8*)dst)[i] = o;
}
__global__ __launch_bounds__(256) void conv2_bf16_kern(
    const float* __restrict__ s1, u16* __restrict__ d1, int n1,
    const float* __restrict__ s2, u16* __restrict__ d2, int n2)
{
    for (int i = blockIdx.x * 256 + threadIdx.x; i < n1 + n2; i += gridDim.x * 256) {
        if (i < n1) conv8(s1, d1, i);
        else        conv8(s2, d2, i - n1);
    }
}

// ---------------- GEMM: C[M,N] = A[M,K] * B[N,K]^T (bf16 in) ----------------
// r10-proven core: 128x128 tile, BK=32, dbuf LDS, counted vmcnt(4), XOR swizzle.
// Wave arrangement 4x1: wave w owns rows [m0+32w, +32) x ALL 128 cols
// (acc[2][8]; same 16 MFMA/iter; 10 ds_read_b128/iter vs 8 at 2x2).
// MODE 0: plain f32 C. MODE 2 (gemm1): fused epilogue — each 128-col tile is
// one head: RMSNorm (in-wave shfl), RoPE (pairs j/j+4 in-thread) -> qr/kr;
// v-heads (40..47) -> transposed vt. Deletes the nr_vt kernel + qkv roundtrip.
template<int MODE>
__global__ __launch_bounds__(256) void gemm_bt(
    const u16* __restrict__ A, const u16* __restrict__ B,
    float* __restrict__ C, int N, int K,
    const float* __restrict__ qw, const float* __restrict__ kw,
    u16* __restrict__ qr, u16* __restrict__ kr, u16* __restrict__ vt)
{
    __shared__ u16 As[2][128 * 32];
    __shared__ u16 Bs[2][128 * 32];
    const int tid = threadIdx.x, lane = tid & 63, wid = tid >> 6;
    const int lg = lane >> 4, l15 = lane & 15;
    const int m0 = blockIdx.y * 128, n0 = blockIdx.x * 128;
    const int srow = wid * 32 + (lane >> 2);
    const int scol = (((lane & 3) ^ ((lane >> 3) & 3))) * 8;
    const u16* ga = &A[(size_t)(m0 + srow) * K + scol];
    const u16* gb = &B[(size_t)(n0 + srow) * K + scol];
    const int rsw = (lg ^ ((l15 >> 1) & 3)) * 8;       // read-side swizzle

    f32x4 acc[2][8] = {};
    const int nk = K >> 5;

    auto stage = [&](int buf, int koff) {
        u16* la = &As[buf][wid * 1024];
        u16* lb = &Bs[buf][wid * 1024];
        gload_lds16(ga + koff, la);
        gload_lds16(ga + koff + 16 * K, la + 512);
        gload_lds16(gb + koff, lb);
        gload_lds16(gb + koff + 16 * K, lb + 512);
    };

    stage(0, 0);
    for (int kk = 0; kk < nk; ++kk) {
        const int cur = kk & 1;
        if (kk + 1 < nk) {
            stage(cur ^ 1, (kk + 1) * 32);
            asm volatile("s_waitcnt vmcnt(4)" ::: "memory");
        } else {
            asm volatile("s_waitcnt vmcnt(0)" ::: "memory");
        }
        __builtin_amdgcn_s_barrier();
        s16x8 af[2], bfr[8];
#pragma unroll
        for (int i = 0; i < 2; ++i) af[i]  = *(const s16x8*)&As[cur][(wid * 32 + i * 16 + l15) * 32 + rsw];
#pragma unroll
        for (int j = 0; j < 8; ++j) bfr[j] = *(const s16x8*)&Bs[cur][(j * 16 + l15) * 32 + rsw];
#pragma unroll
        for (int i = 0; i < 2; ++i)
#pragma unroll
            for (int j = 0; j < 8; ++j)
                acc[i][j] = __builtin_amdgcn_mfma_f32_16x16x32_bf16(af[i], bfr[j], acc[i][j], 0, 0, 0);
        __builtin_amdgcn_s_barrier();
    }

    const int tb = m0 + 32 * wid + lg * 4;             // + i*16 + r = row t
    if (MODE == 0) {
#pragma unroll
        for (int i = 0; i < 2; ++i)
#pragma unroll
            for (int j = 0; j < 8; ++j) {
                int cc = n0 + j * 16 + l15;
#pragma unroll
                for (int r = 0; r < 4; ++r)
                    C[(size_t)(tb + i * 16 + r) * N + cc] = acc[i][j][r];
            }
        return;
    }
    // MODE 2: fused epilogue. head = n0/128.
    const int head = n0 >> 7;
    if (head >= 40) {                                  // V: transposed store
        const int kvh = head - 40;
#pragma unroll
        for (int i = 0; i < 2; ++i)
#pragma unroll
            for (int j = 0; j < 8; ++j) {
                int d = j * 16 + l15;
                s16x4 pk;
#pragma unroll
                for (int r = 0; r < 4; ++r) pk[r] = (short)f2bf(acc[i][j][r]);
                *(s16x4*)&vt[(size_t)(kvh * HD + d) * T_SEQ + tb + i * 16] = pk;
            }
        return;
    }
    const float* wgt = (head < 32) ? qw : kw;
    u16* dst0 = (head < 32) ? (qr + (size_t)head * T_SEQ * HD)
                            : (kr + (size_t)(head - 32) * T_SEQ * HD);
    float wv[8];
#pragma unroll
    for (int j = 0; j < 8; ++j) wv[j] = wgt[j * 16 + l15];
    float iff[4];
#pragma unroll
    for (int j = 0; j < 4; ++j)
        iff[j] = exp2f((float)(j * 16 + l15) * -0.20762050593567985f);
#pragma unroll
    for (int i = 0; i < 2; ++i) {
        float rs[4];
#pragma unroll
        for (int r = 0; r < 4; ++r) {
            float s = 0.f;
#pragma unroll
            for (int j = 0; j < 8; ++j) s += acc[i][j][r] * acc[i][j][r];
#pragma unroll
            for (int d = 1; d < 16; d <<= 1) s += __shfl_xor(s, d);
            rs[r] = rsqrtf(s * (1.0f / 128.0f) + 1e-6f);
        }
#pragma unroll
        for (int r = 0; r < 4; ++r) {
            int t = tb + i * 16 + r;
            u16* dst = dst0 + (size_t)t * HD;
#pragma unroll
            for (int j = 0; j < 4; ++j) {
                float sn, cs;
                sincosf((float)t * iff[j], &sn, &cs);
                float x1 = acc[i][j][r] * rs[r] * wv[j];
                float x2 = acc[i][j + 4][r] * rs[r] * wv[j + 4];
                dst[j * 16 + l15]      = f2bf(x1 * cs - x2 * sn);
                dst[j * 16 + l15 + 64] = f2bf(x2 * cs + x1 * sn);
            }
        }
    }
}

// ---------------- Flash attention (causal, GQA), swapped-QK^T, QBLK=128 --------
// grid (8, NQ) = 256 blocks, 512 thr = 8 waves. Dbuf K/V, 1 barrier/tile.
// Each block also converts its 256KB slice of wo (f32->bf16), software-pipelined
// 1 chunk/thread/K-tile — rides the idle VMEM pipe under MFMA.
#define KS(b, r, c) Ks[(b)][((r) << 7) + ((c) ^ (((r) & 7) << 3))]
#define VS(b, r, c) Vs[(b)][((r) << 6) + ((c) ^ (((r) & 7) << 3))]
#define PS(wv, r, c) Ps[((wv) << 10) + ((r) << 6) + ((c) ^ (((r) & 7) << 3))]

__global__ __launch_bounds__(512) void attn_kern(
    const u16* __restrict__ qr, const u16* __restrict__ kr,
    const u16* __restrict__ vt, u16* __restrict__ o,
    const float* __restrict__ wo, u16* __restrict__ wo_bf)
{
    __shared__ u16 Ks[2][64 * 128];
    __shared__ u16 Vs[2][128 * 64];
    __shared__ u16 Ps[8 * 16 * 64];
    const int tid = threadIdx.x, lane = tid & 63, w = tid >> 6;   // w: 0..7
    const int lg = lane >> 4, l15 = lane & 15;
    const int fb = (int)blockIdx.y * 8 + (int)blockIdx.x;         // 0..255
    const int flat = xcd_swz(fb, 256);
    const int qh = flat >> 3, bx = flat & 7;
    const int kvh = qh >> 2;
    const float scale2 = 0.08838834764831845f * 1.4426950408889634f;  // 1/sqrt(128)*log2e

    const int cvbase = fb * 8192 + tid;   // wo chunks owned by this block
    int cv = 0;
    float4 cva = {}, cvb = {};

    const int krow = tid >> 4, kcol = (tid & 15) * 8;
    const int vrow = tid >> 3, vcol = (tid & 7) * 8;
    const u16* krbase = kr + (size_t)kvh * T_SEQ * HD;
    const u16* vtbase = vt + (size_t)kvh * HD * T_SEQ;

    s16x8 kst[2], vst[2];
#define LOADKV(k0_) do { \
    kst[0] = *(const s16x8*)&krbase[(size_t)((k0_) + krow) * HD + kcol]; \
    kst[1] = *(const s16x8*)&krbase[(size_t)((k0_) + krow + 32) * HD + kcol]; \
    vst[0] = *(const s16x8*)&vtbase[(size_t)(vrow) * T_SEQ + (k0_) + vcol]; \
    vst[1] = *(const s16x8*)&vtbase[(size_t)(vrow + 64) * T_SEQ + (k0_) + vcol]; \
    } while (0)
#define WRITEKV(b) do { \
    *(s16x8*)&KS((b), krow, kcol) = kst[0]; \
    *(s16x8*)&KS((b), krow + 32, kcol) = kst[1]; \
    *(s16x8*)&VS((b), vrow, vcol) = vst[0]; \
    *(s16x8*)&VS((b), vrow + 64, vcol) = vst[1]; \
    } while (0)

    for (int half = 0; half < 2; ++half) {
        const int q0 = (half == 0) ? bx * 128 : (T_SEQ - 128) - bx * 128;
        s16x8 qf[4];
        {
            const u16* qb = qr + ((size_t)qh * T_SEQ + q0 + w * 16 + l15) * HD;
#pragma unroll
            for (int dc = 0; dc < 4; ++dc) qf[dc] = *(const s16x8*)&qb[dc * 32 + lg * 8];
        }
        f32x4 oacc[8] = {};
        float mQ = -1e30f, lsQ = 0.f;

        const int ktiles = (q0 >> 6) + 2;
        LOADKV(0);
        WRITEKV(0);
        __syncthreads();
        for (int kt = 0; kt < ktiles; ++kt) {
            const int k0 = kt * 64;
            const int cur = kt & 1;
            if (kt + 1 < ktiles) LOADKV(k0 + 64);

            if (cv <= 16) {
                if (cv > 0) {
                    s16x8 o8;
                    o8[0] = (short)f2bf(cva.x); o8[1] = (short)f2bf(cva.y);
                    o8[2] = (short)f2bf(cva.z); o8[3] = (short)f2bf(cva.w);
                    o8[4] = (short)f2bf(cvb.x); o8[5] = (short)f2bf(cvb.y);
                    o8[6] = (short)f2bf(cvb.z); o8[7] = (short)f2bf(cvb.w);
                    ((s16x8*)wo_bf)[cvbase + (cv - 1) * 512] = o8;
                }
                if (cv < 16) {
                    cva = ((const float4*)wo)[2 * (cvbase + cv * 512)];
                    cvb = ((const float4*)wo)[2 * (cvbase + cv * 512) + 1];
                }
                ++cv;
            }

            f32x4 sc[4] = {};
            __builtin_amdgcn_s_setprio(1);
#pragma unroll
            for (int nc = 0; nc < 4; ++nc)
#pragma unroll
                for (int dc = 0; dc < 4; ++dc) {
                    s16x8 kf = *(const s16x8*)&KS(cur, nc * 16 + l15, dc * 32 + lg * 8);
                    sc[nc] = __builtin_amdgcn_mfma_f32_16x16x32_bf16(kf, qf[dc], sc[nc], 0, 0, 0);
                }
            __builtin_amdgcn_s_setprio(0);

            const int qg = q0 + w * 16 + l15;
            const bool needMask = (k0 + 63) > (q0 + w * 16);
            float tm = -1e30f;
#pragma unroll
            for (int nc = 0; nc < 4; ++nc)
#pragma unroll
                for (int r = 0; r < 4; ++r) {
                    float v = sc[nc][r] * scale2;
                    int kg = k0 + nc * 16 + lg * 4 + r;
                    if (needMask && kg > qg) v = -1e30f;
                    sc[nc][r] = v;
                    tm = fmaxf(tm, v);
                }
            tm = fmaxf(tm, __shfl_xor(tm, 16));
            tm = fmaxf(tm, __shfl_xor(tm, 32));

            if (__any(tm > mQ + 8.0f)) {
                float mn = fmaxf(mQ, tm);
                float alpha = exp2f(mQ - mn);
                mQ = mn;
                lsQ *= alpha;
                float aq[4];
#pragma unroll
                for (int r = 0; r < 4; ++r) aq[r] = __shfl(alpha, lg * 4 + r);
#pragma unroll
                for (int dc = 0; dc < 8; ++dc)
#pragma unroll
                    for (int r = 0; r < 4; ++r) oacc[dc][r] *= aq[r];
            }

            float ts = 0.f;
#pragma unroll
            for (int nc = 0; nc < 4; ++nc) {
                s16x4 pk;
#pragma unroll
                for (int r = 0; r < 4; ++r) {
                    float e = exp2f(sc[nc][r] - mQ);
                    ts += e;
                    pk[r] = (short)f2bf(e);
                }
                *(s16x4*)&PS(w, l15, nc * 16 + lg * 4) = pk;
            }
            ts += __shfl_xor(ts, 16);
            ts += __shfl_xor(ts, 32);
            lsQ += ts;

            __builtin_amdgcn_s_setprio(1);
#pragma unroll
            for (int kc = 0; kc < 2; ++kc) {
                s16x8 pf = *(const s16x8*)&PS(w, l15, kc * 32 + lg * 8);
#pragma unroll
                for (int dc = 0; dc < 8; ++dc) {
                    s16x8 vf = *(const s16x8*)&VS(cur, dc * 16 + l15, kc * 32 + lg * 8);
                    oacc[dc] = __builtin_amdgcn_mfma_f32_16x16x32_bf16(pf, vf, oacc[dc], 0, 0, 0);
                }
            }
            __builtin_amdgcn_s_setprio(0);

            if (kt + 1 < ktiles) WRITEKV(cur ^ 1);
            __syncthreads();
        }
        float lq[4];
#pragma unroll
        for (int r = 0; r < 4; ++r) lq[r] = __shfl(lsQ, lg * 4 + r);
#pragma unroll
        for (int r = 0; r < 4; ++r) {
            float inv = 1.0f / lq[r];
            int trow = q0 + w * 16 + lg * 4 + r;
            u16* dst = o + (size_t)trow * (NQ * HD) + qh * HD;
#pragma unroll
            for (int dc = 0; dc < 8; ++dc) dst[dc * 16 + l15] = f2bf(oacc[dc][r] * inv);
        }
    }
#undef LOADKV
#undef WRITEKV
}

extern "C" void kernel_launch(void* const* d_in, const int* in_sizes, int n_in,
                              void* d_out, int out_size, void* d_ws, size_t ws_size,
                              hipStream_t stream)
{
    const float* hs   = (const float*)d_in[0];
    const float* wqkv = (const float*)d_in[1];
    const float* qw   = (const float*)d_in[2];
    const float* kw   = (const float*)d_in[3];
    const float* wo   = (const float*)d_in[4];
    float* out = (float*)d_out;

    // workspace 92,274,688 B (88 MiB), no live-region overlap:
    //   [ 0,16M)  hs_bf  -> ob (attn output; hs_bf dead after gemm1)
    //   [16,32M)  qr    [32,36M) kr    [36,40M) vt
    //   [40,88M)  wqkv_bf (dead after gemm1) -> wo_bf[40,72M) written by attn
    char* ws = (char*)d_ws;
    u16* hs_bf   = (u16*)(ws);
    u16* ob      = (u16*)(ws);
    u16* qr      = (u16*)(ws + 16777216);
    u16* kr      = (u16*)(ws + 33554432);
    u16* vt      = (u16*)(ws + 37748736);
    u16* wo_bf   = (u16*)(ws + 41943040);
    u16* wqkv_bf = (u16*)(ws + 41943040);

    // 1) convert hs + wqkv
    conv2_bf16_kern<<<2048, 256, 0, stream>>>(
        hs, hs_bf, T_SEQ * HIDDEN / 8, wqkv, wqkv_bf, QKV_N * HIDDEN / 8);
    // 2) gemm1 with fused RMSNorm+RoPE+V-transpose epilogue -> qr, kr, vt
    gemm_bt<2><<<dim3(QKV_N / 128, T_SEQ / 128), 256, 0, stream>>>(
        hs_bf, wqkv_bf, nullptr, QKV_N, HIDDEN, qw, kw, qr, kr, vt);
    // 3) attention with embedded wo conversion (wo_bf overwrites dead wqkv_bf)
    attn_kern<<<dim3(8, NQ), 512, 0, stream>>>(qr, kr, vt, ob, wo, wo_bf);
    // 4) out = o @ wo^T
    gemm_bt<0><<<dim3(HIDDEN / 128, T_SEQ / 128), 256, 0, stream>>>(
        ob, wo_bf, out, HIDDEN, HIDDEN, nullptr, nullptr, nullptr, nullptr, nullptr);
}

// Round 14
// 331.390 us; speedup vs baseline: 1.3594x; 1.1192x over previous
//
#include <hip/hip_runtime.h>
#include <hip/hip_bf16.h>

typedef float f32x4 __attribute__((ext_vector_type(4)));
typedef short s16x8 __attribute__((ext_vector_type(8)));
typedef short s16x4 __attribute__((ext_vector_type(4)));
typedef unsigned short u16;

#define HIDDEN 4096
#define NQ 32
#define NKV 8
#define HD 128
#define T_SEQ 2048
#define QKV_N ((NQ + 2 * NKV) * HD)   // 6144

__device__ __forceinline__ u16 f2bf(float f) {
    union { float f; unsigned u; } v; v.f = f;
    unsigned r = v.u + 0x7FFFu + ((v.u >> 16) & 1u);
    return (u16)(r >> 16);
}
__device__ __forceinline__ float b2f(u16 h) {
    union { unsigned u; float f; } v; v.u = ((unsigned)h) << 16; return v.f;
}
__device__ __forceinline__ void gload_lds16(const u16* g, u16* l) {
    __builtin_amdgcn_global_load_lds(
        (const __attribute__((address_space(1))) unsigned int*)g,
        (__attribute__((address_space(3))) unsigned int*)l,
        16, 0, 0);
}
// bijective XCD remap (nwg % 8 == 0): contiguous chunk per XCD
__device__ __forceinline__ int xcd_swz(int flat, int nwg) {
    return (flat & 7) * (nwg >> 3) + (flat >> 3);
}

// ---------------- f32 -> bf16 bulk convert (two segments) ----------------
__device__ __forceinline__ void conv8(const float* src, u16* dst, int i) {
    const float4 a = ((const float4*)src)[2 * i];
    const float4 b = ((const float4*)src)[2 * i + 1];
    s16x8 o;
    o[0] = (short)f2bf(a.x); o[1] = (short)f2bf(a.y);
    o[2] = (short)f2bf(a.z); o[3] = (short)f2bf(a.w);
    o[4] = (short)f2bf(b.x); o[5] = (short)f2bf(b.y);
    o[6] = (short)f2bf(b.z); o[7] = (short)f2bf(b.w);
    ((s16x8*)dst)[i] = o;
}
__global__ __launch_bounds__(256) void conv2_bf16_kern(
    const float* __restrict__ s1, u16* __restrict__ d1, int n1,
    const float* __restrict__ s2, u16* __restrict__ d2, int n2)
{
    for (int i = blockIdx.x * 256 + threadIdx.x; i < n1 + n2; i += gridDim.x * 256) {
        if (i < n1) conv8(s1, d1, i);
        else        conv8(s2, d2, i - n1);
    }
}

// ---------------- GEMM: C[M,N] = A[M,K] * B[N,K]^T (bf16 in) ----------------
// 128x128 tile, BK=32, 4 waves 2x2, double-buffered LDS, counted vmcnt(4),
// XOR-swizzled k-chunks; linear LDS dest + pre-swizzled global source.
template<int OUT_BF16>
__global__ __launch_bounds__(256) void gemm_bt_bf16(
    const u16* __restrict__ A, const u16* __restrict__ B,
    void* __restrict__ Cv, int N, int K)
{
    __shared__ u16 As[2][128 * 32];
    __shared__ u16 Bs[2][128 * 32];
    const int tid = threadIdx.x, lane = tid & 63, wid = tid >> 6;
    const int wr = wid >> 1, wc = wid & 1, lg = lane >> 4, l15 = lane & 15;
    const int m0 = blockIdx.y * 128, n0 = blockIdx.x * 128;
    const int srow = wid * 32 + (lane >> 2);
    const int scol = (((lane & 3) ^ ((lane >> 3) & 3))) * 8;
    const u16* ga = &A[(size_t)(m0 + srow) * K + scol];
    const u16* gb = &B[(size_t)(n0 + srow) * K + scol];
    const int rsw = (lg ^ ((l15 >> 1) & 3)) * 8;

    f32x4 acc[4][4] = {};
    const int nk = K >> 5;

    auto stage = [&](int buf, int koff) {
        u16* la = &As[buf][wid * 1024];
        u16* lb = &Bs[buf][wid * 1024];
        gload_lds16(ga + koff, la);
        gload_lds16(ga + koff + 16 * K, la + 512);
        gload_lds16(gb + koff, lb);
        gload_lds16(gb + koff + 16 * K, lb + 512);
    };

    stage(0, 0);
    for (int kk = 0; kk < nk; ++kk) {
        const int cur = kk & 1;
        if (kk + 1 < nk) {
            stage(cur ^ 1, (kk + 1) * 32);
            asm volatile("s_waitcnt vmcnt(4)" ::: "memory");
        } else {
            asm volatile("s_waitcnt vmcnt(0)" ::: "memory");
        }
        __builtin_amdgcn_s_barrier();
        s16x8 af[4], bfr[4];
#pragma unroll
        for (int i = 0; i < 4; ++i) af[i]  = *(const s16x8*)&As[cur][(wr * 64 + i * 16 + l15) * 32 + rsw];
#pragma unroll
        for (int j = 0; j < 4; ++j) bfr[j] = *(const s16x8*)&Bs[cur][(wc * 64 + j * 16 + l15) * 32 + rsw];
#pragma unroll
        for (int i = 0; i < 4; ++i)
#pragma unroll
            for (int j = 0; j < 4; ++j)
                acc[i][j] = __builtin_amdgcn_mfma_f32_16x16x32_bf16(af[i], bfr[j], acc[i][j], 0, 0, 0);
        __builtin_amdgcn_s_barrier();
    }
#pragma unroll
    for (int i = 0; i < 4; ++i) {
        int r0 = m0 + wr * 64 + i * 16 + lg * 4;
#pragma unroll
        for (int j = 0; j < 4; ++j) {
            int cc = n0 + wc * 64 + j * 16 + l15;
#pragma unroll
            for (int r = 0; r < 4; ++r) {
                if (OUT_BF16)
                    ((u16*)Cv)[(size_t)(r0 + r) * N + cc] = f2bf(acc[i][j][r]);
                else
                    ((float*)Cv)[(size_t)(r0 + r) * N + cc] = acc[i][j][r];
            }
        }
    }
}

// ---------------- Fused RMSNorm+RoPE and V-transpose ----------------
// 1D grid 20736 blocks x 256 thr:
//   id < 20480: norm+rope. t = id & 2047, head-group = id >> 11 (4 heads/block).
//   id >= 20480: vtrans.  id2 = id-20480: t0 = (id2 & 31)*64, kh = id2 >> 5.
__global__ __launch_bounds__(256) void nr_vt_kern(
    const u16* __restrict__ qkv, const float* __restrict__ qw,
    const float* __restrict__ kw, u16* __restrict__ qr, u16* __restrict__ kr,
    u16* __restrict__ vt)
{
    __shared__ u16 Ts[128][66];
    const int id = blockIdx.x, tid = threadIdx.x;
    if (id < 20480) {
        const int t = id & 2047, h = (id >> 11) * 4 + (tid >> 6);
        const int i = tid & 63;
        const size_t rowbase = (size_t)t * QKV_N;
        const u16* src; const float* w; u16* dst;
        if (h < 32) {
            src = qkv + rowbase + h * HD; w = qw;
            dst = qr + ((size_t)h * T_SEQ + t) * HD;
        } else {
            int kh = h - 32;
            src = qkv + rowbase + NQ * HD + kh * HD; w = kw;
            dst = kr + ((size_t)kh * T_SEQ + t) * HD;
        }
        float x1 = b2f(src[i]), x2 = b2f(src[i + 64]);
        float ss = x1 * x1 + x2 * x2;
#pragma unroll
        for (int d = 32; d >= 1; d >>= 1) ss += __shfl_xor(ss, d);
        float rs = rsqrtf(ss * (1.0f / 128.0f) + 1e-6f);
        x1 *= rs * w[i];
        x2 *= rs * w[i + 64];
        float ang = (float)t * exp2f((float)i * -0.20762050593567985f);
        float sn, cs;
        sincosf(ang, &sn, &cs);
        dst[i]      = f2bf(x1 * cs - x2 * sn);
        dst[i + 64] = f2bf(x2 * cs + x1 * sn);
        return;
    }
    const int id2 = id - 20480;
    const int t0 = (id2 & 31) * 64, kh = id2 >> 5;
#pragma unroll
    for (int it = 0; it < 4; ++it) {
        int slot = tid + it * 256;
        int tl = slot >> 4, dc = (slot & 15) * 8;
        s16x8 v = *(const s16x8*)&qkv[(size_t)(t0 + tl) * QKV_N + (NQ + NKV) * HD + kh * HD + dc];
#pragma unroll
        for (int e = 0; e < 8; ++e) Ts[dc + e][tl] = (u16)v[e];
    }
    __syncthreads();
#pragma unroll
    for (int it = 0; it < 4; ++it) {
        int slot = tid + it * 256;
        int d = slot >> 3, c = (slot & 7) * 8;
        s16x8 v = *(const s16x8*)&Ts[d][c];
        *(s16x8*)&vt[((size_t)kh * HD + d) * T_SEQ + t0 + c] = v;
    }
}

// ---------------- Flash attention (causal, GQA), swapped-QK^T, QBLK=128 --------
// grid (8, NQ) = 256 blocks, 512 thr = 8 waves. Dbuf K/V, 1 barrier/tile.
// Each block ALSO converts its 256KB slice of wo (f32->bf16), software-pipelined
// 1 chunk/thread/K-tile (load at tile t, store at t+1): rides the idle VMEM pipe
// under MFMA — no cross-block scheduling assumption (r9 lesson).
#define KS(b, r, c) Ks[(b)][((r) << 7) + ((c) ^ (((r) & 7) << 3))]
#define VS(b, r, c) Vs[(b)][((r) << 6) + ((c) ^ (((r) & 7) << 3))]
#define PS(wv, r, c) Ps[((wv) << 10) + ((r) << 6) + ((c) ^ (((r) & 7) << 3))]

__global__ __launch_bounds__(512) void attn_kern(
    const u16* __restrict__ qr, const u16* __restrict__ kr,
    const u16* __restrict__ vt, u16* __restrict__ o,
    const float* __restrict__ wo, u16* __restrict__ wo_bf)
{
    __shared__ u16 Ks[2][64 * 128];
    __shared__ u16 Vs[2][128 * 64];
    __shared__ u16 Ps[8 * 16 * 64];
    const int tid = threadIdx.x, lane = tid & 63, w = tid >> 6;   // w: 0..7
    const int lg = lane >> 4, l15 = lane & 15;
    const int fb = (int)blockIdx.y * 8 + (int)blockIdx.x;         // 0..255
    const int flat = xcd_swz(fb, 256);
    const int qh = flat >> 3, bx = flat & 7;
    const int kvh = qh >> 2;
    const float scale2 = 0.08838834764831845f * 1.4426950408889634f;  // 1/sqrt(128)*log2e

    // wo-conversion slice: block fb owns chunks [fb*8192, fb*8192+8192)
    const int cvbase = fb * 8192 + tid;   // + cv*512
    int cv = 0;
    float4 cva = {}, cvb = {};

    const int krow = tid >> 4, kcol = (tid & 15) * 8;
    const int vrow = tid >> 3, vcol = (tid & 7) * 8;
    const u16* krbase = kr + (size_t)kvh * T_SEQ * HD;
    const u16* vtbase = vt + (size_t)kvh * HD * T_SEQ;

    s16x8 kst[2], vst[2];
#define LOADKV(k0_) do { \
    kst[0] = *(const s16x8*)&krbase[(size_t)((k0_) + krow) * HD + kcol]; \
    kst[1] = *(const s16x8*)&krbase[(size_t)((k0_) + krow + 32) * HD + kcol]; \
    vst[0] = *(const s16x8*)&vtbase[(size_t)(vrow) * T_SEQ + (k0_) + vcol]; \
    vst[1] = *(const s16x8*)&vtbase[(size_t)(vrow + 64) * T_SEQ + (k0_) + vcol]; \
    } while (0)
#define WRITEKV(b) do { \
    *(s16x8*)&KS((b), krow, kcol) = kst[0]; \
    *(s16x8*)&KS((b), krow + 32, kcol) = kst[1]; \
    *(s16x8*)&VS((b), vrow, vcol) = vst[0]; \
    *(s16x8*)&VS((b), vrow + 64, vcol) = vst[1]; \
    } while (0)

    for (int half = 0; half < 2; ++half) {
        const int q0 = (half == 0) ? bx * 128 : (T_SEQ - 128) - bx * 128;
        s16x8 qf[4];
        {
            const u16* qb = qr + ((size_t)qh * T_SEQ + q0 + w * 16 + l15) * HD;
#pragma unroll
            for (int dc = 0; dc < 4; ++dc) qf[dc] = *(const s16x8*)&qb[dc * 32 + lg * 8];
        }
        f32x4 oacc[8] = {};
        float mQ = -1e30f, lsQ = 0.f;

        const int ktiles = (q0 >> 6) + 2;
        LOADKV(0);
        WRITEKV(0);
        __syncthreads();
        for (int kt = 0; kt < ktiles; ++kt) {
            const int k0 = kt * 64;
            const int cur = kt & 1;
            if (kt + 1 < ktiles) LOADKV(k0 + 64);

            // pipelined wo conversion: store chunk cv-1 (loaded last tile), load cv.
            // Total 34 k-tiles per block >= 17 needed; cv is block-uniform.
            if (cv <= 16) {
                if (cv > 0) {
                    s16x8 o8;
                    o8[0] = (short)f2bf(cva.x); o8[1] = (short)f2bf(cva.y);
                    o8[2] = (short)f2bf(cva.z); o8[3] = (short)f2bf(cva.w);
                    o8[4] = (short)f2bf(cvb.x); o8[5] = (short)f2bf(cvb.y);
                    o8[6] = (short)f2bf(cvb.z); o8[7] = (short)f2bf(cvb.w);
                    ((s16x8*)wo_bf)[cvbase + (cv - 1) * 512] = o8;
                }
                if (cv < 16) {
                    cva = ((const float4*)wo)[2 * (cvbase + cv * 512)];
                    cvb = ((const float4*)wo)[2 * (cvbase + cv * 512) + 1];
                }
                ++cv;
            }

            f32x4 sc[4] = {};
            __builtin_amdgcn_s_setprio(1);
#pragma unroll
            for (int nc = 0; nc < 4; ++nc)
#pragma unroll
                for (int dc = 0; dc < 4; ++dc) {
                    s16x8 kf = *(const s16x8*)&KS(cur, nc * 16 + l15, dc * 32 + lg * 8);
                    sc[nc] = __builtin_amdgcn_mfma_f32_16x16x32_bf16(kf, qf[dc], sc[nc], 0, 0, 0);
                }
            __builtin_amdgcn_s_setprio(0);

            const int qg = q0 + w * 16 + l15;
            const bool needMask = (k0 + 63) > (q0 + w * 16);
            float tm = -1e30f;
#pragma unroll
            for (int nc = 0; nc < 4; ++nc)
#pragma unroll
                for (int r = 0; r < 4; ++r) {
                    float v = sc[nc][r] * scale2;
                    int kg = k0 + nc * 16 + lg * 4 + r;
                    if (needMask && kg > qg) v = -1e30f;
                    sc[nc][r] = v;
                    tm = fmaxf(tm, v);
                }
            tm = fmaxf(tm, __shfl_xor(tm, 16));
            tm = fmaxf(tm, __shfl_xor(tm, 32));

            if (__any(tm > mQ + 8.0f)) {
                float mn = fmaxf(mQ, tm);
                float alpha = exp2f(mQ - mn);
                mQ = mn;
                lsQ *= alpha;
                float aq[4];
#pragma unroll
                for (int r = 0; r < 4; ++r) aq[r] = __shfl(alpha, lg * 4 + r);
#pragma unroll
                for (int dc = 0; dc < 8; ++dc)
#pragma unroll
                    for (int r = 0; r < 4; ++r) oacc[dc][r] *= aq[r];
            }

            float ts = 0.f;
#pragma unroll
            for (int nc = 0; nc < 4; ++nc) {
                s16x4 pk;
#pragma unroll
                for (int r = 0; r < 4; ++r) {
                    float e = exp2f(sc[nc][r] - mQ);
                    ts += e;
                    pk[r] = (short)f2bf(e);
                }
                *(s16x4*)&PS(w, l15, nc * 16 + lg * 4) = pk;
            }
            ts += __shfl_xor(ts, 16);
            ts += __shfl_xor(ts, 32);
            lsQ += ts;

            __builtin_amdgcn_s_setprio(1);
#pragma unroll
            for (int kc = 0; kc < 2; ++kc) {
                s16x8 pf = *(const s16x8*)&PS(w, l15, kc * 32 + lg * 8);
#pragma unroll
                for (int dc = 0; dc < 8; ++dc) {
                    s16x8 vf = *(const s16x8*)&VS(cur, dc * 16 + l15, kc * 32 + lg * 8);
                    oacc[dc] = __builtin_amdgcn_mfma_f32_16x16x32_bf16(pf, vf, oacc[dc], 0, 0, 0);
                }
            }
            __builtin_amdgcn_s_setprio(0);

            if (kt + 1 < ktiles) WRITEKV(cur ^ 1);
            __syncthreads();
        }
        float lq[4];
#pragma unroll
        for (int r = 0; r < 4; ++r) lq[r] = __shfl(lsQ, lg * 4 + r);
#pragma unroll
        for (int r = 0; r < 4; ++r) {
            float inv = 1.0f / lq[r];
            int trow = q0 + w * 16 + lg * 4 + r;
            u16* dst = o + (size_t)trow * (NQ * HD) + qh * HD;
#pragma unroll
            for (int dc = 0; dc < 8; ++dc) dst[dc * 16 + l15] = f2bf(oacc[dc][r] * inv);
        }
    }
#undef LOADKV
#undef WRITEKV
}

extern "C" void kernel_launch(void* const* d_in, const int* in_sizes, int n_in,
                              void* d_out, int out_size, void* d_ws, size_t ws_size,
                              hipStream_t stream)
{
    const float* hs   = (const float*)d_in[0];
    const float* wqkv = (const float*)d_in[1];
    const float* qw   = (const float*)d_in[2];
    const float* kw   = (const float*)d_in[3];
    const float* wo   = (const float*)d_in[4];
    float* out = (float*)d_out;

    // workspace layout, 92,274,688 B total; regions reused across disjoint lifetimes:
    //   [ 0,16M)  hs_bf      -> ob (after gemm1)
    //   [16,40M)  qr[16,32M), kr[32,36M), vt[36,40M)
    //   [40,72M)  wo_bf (written during attn; overlaps dead qkv_bf tail)
    //   [64,88M)  qkv_bf (dead after nr_vt)
    char* ws = (char*)d_ws;
    u16* hs_bf   = (u16*)(ws);
    u16* ob      = (u16*)(ws);
    u16* qr      = (u16*)(ws + 16777216);
    u16* kr      = (u16*)(ws + 33554432);
    u16* vt      = (u16*)(ws + 37748736);
    u16* wo_bf   = (u16*)(ws + 41943040);
    u16* qkv_bf  = (u16*)(ws + 67108864);

    // 1) convert hs + wqkv (wqkv_bf shares the qkv_bf..end region? no —
    //    wqkv_bf lives at [40,88M)? It must not overlap qkv_bf [64,88M).
    //    Layout identical to r10: wqkv_bf converted into [40,64M)+[64..? see below)
    // r10 layout: conv2 wrote wqkv_bf at 16M..64M? No — r10 wrote hs_bf[0,16M) and
    // wqkv_bf via conv2 to the SAME addresses as r8: wqkv_bf base = ws+16M is qr.
    // To match r10 exactly: qkv_bf at [64,88M), gemm1 writes it; conv2 writes
    // wqkv_bf where? r10's conv2 call: (wqkv -> ws+41943040? ) — r10 used
    // wqkv_bf implicitly at wo_bf's slot BEFORE attn ran. Reproduce r10 exactly:
    conv2_bf16_kern<<<2048, 256, 0, stream>>>(
        hs, hs_bf, T_SEQ * HIDDEN / 8, wqkv, (u16*)(ws + 41943040), QKV_N * HIDDEN / 8);
    // 2) qkv = hs @ wqkv^T  (B = wqkv_bf at [40,64M)+... 24.5M region, disjoint
    //    from qkv_bf write target [64,88M))
    gemm_bt_bf16<1><<<dim3(QKV_N / 128, T_SEQ / 128), 256, 0, stream>>>(
        hs_bf, (u16*)(ws + 41943040), (void*)qkv_bf, QKV_N, HIDDEN);
    // 3) fused norm+rope / V-transpose (last readers of qkv_bf)
    nr_vt_kern<<<20736, 256, 0, stream>>>(qkv_bf, qw, kw, qr, kr, vt);
    // 4) attention with embedded wo conversion (wo_bf overwrites dead wqkv_bf)
    attn_kern<<<dim3(8, NQ), 512, 0, stream>>>(qr, kr, vt, ob, wo, wo_bf);
    // 5) out = o @ wo^T
    gemm_bt_bf16<0><<<dim3(HIDDEN / 128, T_SEQ / 128), 256, 0, stream>>>(
        ob, wo_bf, (void*)out, HIDDEN, HIDDEN);
}